// Round 4
// baseline (233.748 us; speedup 1.0000x reference)
//
#include <hip/hip_runtime.h>

#define B_ 32
#define T_ 2048
#define H_ 256
#define L_ 2049   // T_ + 1
#define NBLK (T_ / 64)  // 32 chain blocks of 64 steps (fallback path)

// ---------------- wave reduce helpers (wave = 64 lanes) ----------------
__device__ inline double waveReduceD(double v) {
#pragma unroll
  for (int off = 32; off > 0; off >>= 1) v += __shfl_xor(v, off, 64);
  return v;
}

// ---------------- K0: fold the two linear layers ----------------
// v[c] = sum_o W2[o] * W1[o,c]   (c in [0,512)),  c0 = W2.b1 + b2
__global__ void __launch_bounds__(256) k0_fold(
    const float* __restrict__ W1, const float* __restrict__ b1,
    const float* __restrict__ W2, const float* __restrict__ b2,
    double* __restrict__ vd, double* __restrict__ c0) {
  int c = blockIdx.x * 256 + threadIdx.x;  // 0..511
  double acc = 0.0;
#pragma unroll 8
  for (int o = 0; o < 512; ++o) acc += (double)W2[o] * (double)W1[o * 512 + c];
  vd[c] = acc;
  if (blockIdx.x == 0) {
    __shared__ double red[256];
    double p = (double)W2[threadIdx.x] * (double)b1[threadIdx.x] +
               (double)W2[threadIdx.x + 256] * (double)b1[threadIdx.x + 256];
    red[threadIdx.x] = p;
    __syncthreads();
    for (int s = 128; s > 0; s >>= 1) {
      if (threadIdx.x < s) red[threadIdx.x] += red[threadIdx.x + s];
      __syncthreads();
    }
    if (threadIdx.x == 0) c0[0] = red[0] + (double)b2[0];
  }
}

// ---------------- K1: per-(b,t) row dots ----------------
// d1[r] = x_row.(v1+v2), d2[r] = x_row.v2, absS[r] = (any nonzero) ? 1 : 0
__global__ void __launch_bounds__(256) k1_rowdots(
    const float* __restrict__ x, const double* __restrict__ vd,
    double* __restrict__ d1, double* __restrict__ d2, float* __restrict__ absS) {
  int wave = threadIdx.x >> 6, lane = threadIdx.x & 63;
  long row = (long)blockIdx.x * 4 + wave;  // < B_*T_
  const float4* xr = (const float4*)(x + row * H_);
  float4 xa = xr[lane];
  int base = lane * 4;
  double va0 = vd[base + 0], va1 = vd[base + 1], va2 = vd[base + 2], va3 = vd[base + 3];
  double vb0 = vd[256 + base + 0], vb1 = vd[256 + base + 1],
         vb2 = vd[256 + base + 2], vb3 = vd[256 + base + 3];
  double p2 = (double)xa.x * vb0 + (double)xa.y * vb1 + (double)xa.z * vb2 + (double)xa.w * vb3;
  double p1 = (double)xa.x * (va0 + vb0) + (double)xa.y * (va1 + vb1) +
              (double)xa.z * (va2 + vb2) + (double)xa.w * (va3 + vb3);
  bool nz = (xa.x != 0.0f) || (xa.y != 0.0f) || (xa.z != 0.0f) || (xa.w != 0.0f);
  unsigned long long bal = __ballot(nz);
  p1 = waveReduceD(p1);
  p2 = waveReduceD(p2);
  if (lane == 0) {
    d1[row] = p1;
    d2[row] = p2;
    absS[row] = bal ? 1.0f : 0.0f;
  }
}

// ---------------- K2: weights, scaling, fire extraction (1 block / b) ----
// Fire chain closed form (valid when all scaled w <= 1, i.e. scale <= 1):
//   S_t = cumsum(w), C_t = max(0, ceil(S_t - 1)), fire_t = C_t > C_{t-1},
//   rank of fire = C_t - 1.  Proof: C_t = C_{t-1} + [S_t - C_{t-1} > 1]
//   and w_t <= 1 keeps ceil(S_t-1) within C_{t-1}+1.
__global__ void __launch_bounds__(256) k2_weights(
    const double* __restrict__ d1, const double* __restrict__ d2,
    const float* __restrict__ absS, const float* __restrict__ mask,
    const int* __restrict__ is_tr, const double* __restrict__ c0p,
    float* __restrict__ o_ori, float* __restrict__ o_sa, float* __restrict__ o_ff,
    float* __restrict__ wsc, int* __restrict__ fireT, int* __restrict__ outPos,
    int* __restrict__ nAllArr, int* __restrict__ nUnmArr) {
  __shared__ double s_d2[T_];                   // 16 KB; reused as scaled-w (double)
  __shared__ float s_wf[T_];                    // 8 KB scaled+masked w (f32, k3/fallback)
  __shared__ double red[256];                   // reductions
  __shared__ double s_wtot[4];                  // wave scan totals
  __shared__ int s_int[2];                      // [0]=C@firstPad, [1]=nA
  __shared__ unsigned long long s_mask[NBLK];   // fallback bitmasks
  __shared__ int s_ppc[NBLK];                   // fallback prefix popcounts
  int b = blockIdx.x, tid = threadIdx.x;
  const double* d1b = d1 + (long)b * T_;
  const double* d2b = d2 + (long)b * T_;
  const float* asb = absS + (long)b * T_;
  double c0 = c0p[0];

  // stage d2 into LDS (coalesced) for the window sums
  for (int i = tid; i < T_; i += 256) s_d2[i] = d2b[i];
  __syncthreads();

  // ---- Part A: w = clip(relu(d1 - windowmean(d2) + c0), 0, 1)  (unscaled)
  double wd[8];
  double sa = 0.0, fpc = 0.0;
#pragma unroll
  for (int k = 0; k < 8; ++k) {
    int t = tid + k * 256;
    double wv;
    if (t == 0) {
      wv = d1b[0] - s_d2[0] + c0;  // hist[0] = x[0]
    } else if (t < 10) {
      double hs = 0.0;
      for (int u = 0; u < t; ++u) hs += s_d2[u];
      wv = d1b[t] - hs / (double)t + c0;
    } else {
      double hs = 0.0;
#pragma unroll
      for (int u = 1; u <= 10; ++u) hs += s_d2[t - u];
      wv = d1b[t] - hs / 10.0 + c0;
    }
    wv = wv < 0.0 ? 0.0 : (wv > 1.0 ? 1.0 : wv);
    wd[k] = wv;
    o_ori[(long)b * T_ + t] = (float)wv;
    sa += wv;
    fpc += (asb[t] != 0.0f) ? 1.0 : 0.0;
  }
  // reductions: sum_a, first_pad count, mask sum
  red[tid] = sa; __syncthreads();
  for (int s = 128; s > 0; s >>= 1) { if (tid < s) red[tid] += red[tid + s]; __syncthreads(); }
  double sumA = red[0]; __syncthreads();
  red[tid] = fpc; __syncthreads();
  for (int s = 128; s > 0; s >>= 1) { if (tid < s) red[tid] += red[tid + s]; __syncthreads(); }
  double fpD = red[0]; __syncthreads();
  double ms = 0.0;
  for (int t = tid; t < 200; t += 256) ms += (double)mask[(long)b * 200 + t];
  red[tid] = ms; __syncthreads();
  for (int s = 128; s > 0; s >>= 1) { if (tid < s) red[tid] += red[tid + s]; __syncthreads(); }
  double maskSum = red[0]; __syncthreads();
  if (tid == 0) o_sa[b] = (float)sumA;
  int firstPad = (int)(fpD + 0.5);
  double scale;
  if (is_tr[0] != 0) {
    scale = (sumA == 0.0) ? 0.0 : (maskSum - 1.0) / (sumA > 1e-8 ? sumA : 1e-8);
  } else {
    scale = 1.0;
  }

  // scaled + pad-masked w -> s_d2 (double, reused) + s_wf (f32) + global
  double* s_wd = s_d2;  // s_d2 contents dead past this point
#pragma unroll
  for (int k = 0; k < 8; ++k) {
    int t = tid + k * 256;
    double wv = wd[k] * scale;
    if (t > firstPad) wv = 0.0;
    s_wd[t] = wv;
    float wf = (float)wv;
    s_wf[t] = wf;
    wsc[(long)b * T_ + t] = wf;
  }
  __syncthreads();

  if (scale <= 1.0) {
    // ---- closed-form path: parallel fp64 cumsum + ceil ----
    int lane = tid & 63, wv_ = tid >> 6;
    int t0 = tid * 8;
    double v[8], r[8];
#pragma unroll
    for (int k = 0; k < 8; ++k) v[k] = s_wd[t0 + k];
    double run = 0.0;
#pragma unroll
    for (int k = 0; k < 8; ++k) { run += v[k]; r[k] = run; }
    // wave-inclusive scan of thread totals
    double sc = run;
#pragma unroll
    for (int off = 1; off < 64; off <<= 1) {
      double n = __shfl_up(sc, off, 64);
      if (lane >= off) sc += n;
    }
    if (lane == 63) s_wtot[wv_] = sc;
    __syncthreads();
    double base = 0.0;
    for (int i = 0; i < wv_; ++i) base += s_wtot[i];
    double excl = base + (sc - run);  // exclusive prefix for this thread
    // fires
    double Sp = excl;
    int Cp = (int)ceil(Sp - 1.0); if (Cp < 0) Cp = 0;
    float flags[8];
#pragma unroll
    for (int k = 0; k < 8; ++k) {
      int t = t0 + k;
      double S = excl + r[k];
      int C = (int)ceil(S - 1.0); if (C < 0) C = 0;
      bool fired = C > Cp;
      flags[k] = fired ? 1.0f : 0.0f;
      if (fired) {
        int rank = C - 1;
        fireT[(long)b * T_ + rank] = t;
        outPos[(long)b * T_ + rank] = (t <= firstPad) ? rank : -1;
      }
      if (t == firstPad) s_int[0] = C;
      Cp = C;
    }
    float4* ffv = (float4*)(o_ff + (long)b * T_ + t0);
    ffv[0] = make_float4(flags[0], flags[1], flags[2], flags[3]);
    ffv[1] = make_float4(flags[4], flags[5], flags[6], flags[7]);
    if (tid == 255) s_int[1] = Cp;  // total fire count
    __syncthreads();
    if (tid == 0) {
      int nA = s_int[1];
      nAllArr[b] = nA;
      nUnmArr[b] = (firstPad >= T_) ? nA : s_int[0];
    }
  } else {
    // ---- fallback: serial chain on wave 0 (matches reference fp32 order;
    // needed only when scale > 1 so scaled w may exceed 1) ----
    float scalef = (float)scale;  (void)scalef;
    if (tid < 64) {
      int lane = tid;
      const float4* sw4 = (const float4*)s_wf;
      float4 cur[16], nxt[16];
#pragma unroll
      for (int k = 0; k < 16; ++k) cur[k] = sw4[k];
      float prev = 0.0f;
      for (int blk = 0; blk < NBLK; ++blk) {
        if (blk + 1 < NBLK) {
#pragma unroll
          for (int k = 0; k < 16; ++k) nxt[k] = sw4[(blk + 1) * 16 + k];
        }
        bool myf = false;
#pragma unroll
        for (int k = 0; k < 16; ++k) {
#define STEP(COMP, IDX)                                   \
          {                                               \
            float wvv = cur[k].COMP;                      \
            float nw = prev + wvv;                        \
            bool fired = nw > 1.0f;                       \
            float fw = wvv - (1.0f - prev);               \
            if ((4 * k + IDX) == lane) myf = fired;       \
            prev = fired ? fw : nw;                       \
          }
          STEP(x, 0) STEP(y, 1) STEP(z, 2) STEP(w, 3)
#undef STEP
        }
        unsigned long long bal = __ballot(myf);
        if (lane == 0) s_mask[blk] = bal;
#pragma unroll
        for (int k = 0; k < 16; ++k) cur[k] = nxt[k];
      }
    }
    __syncthreads();
    if (tid == 0) {
      int run = 0;
      for (int k = 0; k < NBLK; ++k) { s_ppc[k] = run; run += __popcll(s_mask[k]); }
      int nA = run;
      int nU;
      if (firstPad >= T_ - 1) {
        nU = nA;
      } else {
        int fb = firstPad >> 6, bit = firstPad & 63;
        unsigned long long keep =
            (bit == 63) ? ~0ull : ((1ull << (bit + 1)) - 1ull);
        nU = s_ppc[fb] + __popcll(s_mask[fb] & keep);
      }
      nAllArr[b] = nA;
      nUnmArr[b] = nU;
    }
    __syncthreads();
#pragma unroll
    for (int k = 0; k < 8; ++k) {
      int t = tid + k * 256;
      int blkI = t >> 6, bit = t & 63;
      unsigned long long m = s_mask[blkI];
      bool f = (m >> bit) & 1ull;
      o_ff[(long)b * T_ + t] = f ? 1.0f : 0.0f;
      if (f) {
        int rank = s_ppc[blkI] + __popcll(m & ((1ull << bit) - 1ull));
        fireT[(long)b * T_ + rank] = t;
        outPos[(long)b * T_ + rank] = (t <= firstPad) ? rank : -1;
      }
    }
  }
}

// ---------------- K3: segment sums -> normalized cif rows ----------------
// one wave per fired row j in [0, nAll]; j == nAll is the final-state row.
// out_row = x[anchor] + sum_{u=lo..hi} (1-w[u]) * x[u]   (fp32, scan order)
#define MAXR_ 512  // fire count per b ~ mask_sum-1 (~199) << 512
__global__ void __launch_bounds__(64) k3_rows(
    const float* __restrict__ x, const float* __restrict__ wsc,
    const int* __restrict__ fireT, const int* __restrict__ outPos,
    const int* __restrict__ nAllArr, const int* __restrict__ nUnmArr,
    float* __restrict__ cif, float* __restrict__ notpad) {
  int j = blockIdx.x, b = blockIdx.y, lane = threadIdx.x;
  int nA = nAllArr[b];
  if (j > nA) return;
  const int* ftb = fireT + (long)b * T_;
  const int* opb = outPos + (long)b * T_;
  int hi, pos;
  if (j < nA) {
    hi = ftb[j];
    pos = opb[j];
    if (pos < 0) return;  // pad-masked fired row: zeroed & dropped
  } else {
    hi = T_ - 1;          // trailing state fin_s appended as last row
    pos = nUnmArr[b];
  }
  int lo, anchor;
  if (j == 0) { lo = 0; anchor = 0; }            // init state s = x[:,0,:]
  else { anchor = ftb[j - 1]; lo = anchor + 1; } // s reset to x[prev_fire]
  const float* xb = x + (long)b * T_ * H_;
  const float4* xav = (const float4*)(xb + (long)anchor * H_);
  float4 acc = xav[lane];
  const float* wb = wsc + (long)b * T_;
  for (int u = lo; u <= hi; ++u) {
    float f = 1.0f - wb[u];
    const float4* xu = (const float4*)(xb + (long)u * H_);
    float4 xv = xu[lane];
    acc.x += f * xv.x; acc.y += f * xv.y; acc.z += f * xv.z; acc.w += f * xv.w;
  }
  float ss = acc.x * acc.x + acc.y * acc.y + acc.z * acc.z + acc.w * acc.w;
#pragma unroll
  for (int off = 32; off > 0; off >>= 1) ss += __shfl_xor(ss, off, 64);
  float norm = sqrtf(ss);
  float inv = 1.0f / fmaxf(norm, 1e-12f);
  float4 o = make_float4(acc.x * inv, acc.y * inv, acc.z * inv, acc.w * inv);
  float4* crow = (float4*)(cif + ((long)b * L_ + pos) * H_);
  crow[lane] = o;
  if (lane == 0) notpad[(long)b * L_ + pos] = 1.0f;
}

// ---------------- launch ----------------
extern "C" void kernel_launch(void* const* d_in, const int* in_sizes, int n_in,
                              void* d_out, int out_size, void* d_ws, size_t ws_size,
                              hipStream_t stream) {
  const float* x    = (const float*)d_in[0];
  const float* mask = (const float*)d_in[1];
  const float* W1   = (const float*)d_in[2];
  const float* b1   = (const float*)d_in[3];
  const float* W2   = (const float*)d_in[4];
  const float* b2   = (const float*)d_in[5];
  const int*   istr = (const int*)d_in[6];

  float* out = (float*)d_out;
  // output layout (all fp32, concatenated in return order)
  float* o_cif = out;                                  // B*L*H
  float* o_ori = o_cif + (size_t)B_ * L_ * H_;         // B*T
  float* o_ff  = o_ori + (size_t)B_ * T_;              // B*T
  float* o_np  = o_ff  + (size_t)B_ * T_;              // B*L
  float* o_sa  = o_np  + (size_t)B_ * L_;              // B

  // workspace layout (~2.06 MB)
  char* w = (char*)d_ws;
  double* vd   = (double*)w; w += 512 * 8;
  double* c0   = (double*)w; w += 8;
  double* d1   = (double*)w; w += (size_t)B_ * T_ * 8;
  double* d2   = (double*)w; w += (size_t)B_ * T_ * 8;
  float* absS  = (float*)w;  w += (size_t)B_ * T_ * 4;
  float* wsc   = (float*)w;  w += (size_t)B_ * T_ * 4;
  int* fireT   = (int*)w;    w += (size_t)B_ * T_ * 4;
  int* outPos  = (int*)w;    w += (size_t)B_ * T_ * 4;
  int* nAllA   = (int*)w;    w += B_ * 4;
  int* nUnmA   = (int*)w;    w += B_ * 4;

  // zero outputs (cif is mostly zeros; notpad needs zeros)
  hipMemsetAsync(d_out, 0, (size_t)out_size * sizeof(float), stream);

  k0_fold<<<2, 256, 0, stream>>>(W1, b1, W2, b2, vd, c0);
  k1_rowdots<<<(B_ * T_) / 4, 256, 0, stream>>>(x, vd, d1, d2, absS);
  k2_weights<<<B_, 256, 0, stream>>>(d1, d2, absS, mask, istr, c0,
                                     o_ori, o_sa, o_ff, wsc, fireT, outPos,
                                     nAllA, nUnmA);
  k3_rows<<<dim3(MAXR_, B_), 64, 0, stream>>>(x, wsc, fireT, outPos, nAllA, nUnmA,
                                              o_cif, o_np);
}

// Round 5
// 155.535 us; speedup vs baseline: 1.5029x; 1.5029x over previous
//
#include <hip/hip_runtime.h>

#define B_ 32
#define T_ 2048
#define H_ 256
#define L_ 2049   // T_ + 1

// ---------------- wave helpers (wave = 64 lanes) ----------------
__device__ inline double waveReduceD(double v) {
#pragma unroll
  for (int off = 32; off > 0; off >>= 1) v += __shfl_xor(v, off, 64);
  return v;
}

// ---------------- K0: fold the two linear layers ----------------
// v[c] = sum_o W2[o] * W1[o,c]  (c in [0,512)),  c0 = W2.b1 + b2
// 16 blocks x 256 threads: block covers 32 c's, 8 o-slices of 64.
__global__ void __launch_bounds__(256) k0_fold(
    const float* __restrict__ W1, const float* __restrict__ b1,
    const float* __restrict__ W2, const float* __restrict__ b2,
    double* __restrict__ vd, double* __restrict__ c0) {
  __shared__ double s_p[8][32];
  int tid = threadIdx.x;
  int cl = tid & 31, sl = tid >> 5;
  int c = blockIdx.x * 32 + cl;
  double acc = 0.0;
#pragma unroll 8
  for (int o = sl * 64; o < sl * 64 + 64; ++o)
    acc += (double)W2[o] * (double)W1[o * 512 + c];
  s_p[sl][cl] = acc;
  __syncthreads();
  if (sl == 0) {
    double v = 0.0;
#pragma unroll
    for (int i = 0; i < 8; ++i) v += s_p[i][cl];
    vd[c] = v;
  }
  if (blockIdx.x == 0) {
    __shared__ double red[256];
    double p = (double)W2[tid] * (double)b1[tid] +
               (double)W2[tid + 256] * (double)b1[tid + 256];
    red[tid] = p;
    __syncthreads();
    for (int s = 128; s > 0; s >>= 1) {
      if (tid < s) red[tid] += red[tid + s];
      __syncthreads();
    }
    if (tid == 0) c0[0] = red[0] + (double)b2[0];
  }
}

// ---------------- K1: per-(b,t) row dots ----------------
// d1[r] = x_row.(v1+v2), d2[r] = x_row.v2, absS[r] = (any nonzero) ? 1 : 0
__global__ void __launch_bounds__(256) k1_rowdots(
    const float* __restrict__ x, const double* __restrict__ vd,
    double* __restrict__ d1, double* __restrict__ d2, float* __restrict__ absS) {
  int wave = threadIdx.x >> 6, lane = threadIdx.x & 63;
  long row = (long)blockIdx.x * 4 + wave;  // < B_*T_
  const float4* xr = (const float4*)(x + row * H_);
  float4 xa = xr[lane];
  int base = lane * 4;
  double va0 = vd[base + 0], va1 = vd[base + 1], va2 = vd[base + 2], va3 = vd[base + 3];
  double vb0 = vd[256 + base + 0], vb1 = vd[256 + base + 1],
         vb2 = vd[256 + base + 2], vb3 = vd[256 + base + 3];
  double p2 = (double)xa.x * vb0 + (double)xa.y * vb1 + (double)xa.z * vb2 + (double)xa.w * vb3;
  double p1 = (double)xa.x * (va0 + vb0) + (double)xa.y * (va1 + vb1) +
              (double)xa.z * (va2 + vb2) + (double)xa.w * (va3 + vb3);
  bool nz = (xa.x != 0.0f) || (xa.y != 0.0f) || (xa.z != 0.0f) || (xa.w != 0.0f);
  unsigned long long bal = __ballot(nz);
  p1 = waveReduceD(p1);
  p2 = waveReduceD(p2);
  if (lane == 0) {
    d1[row] = p1;
    d2[row] = p2;
    absS[row] = bal ? 1.0f : 0.0f;
  }
}

// ---------------- K2: weights + EXACT parallel fire solve (1 block / b) --
// prev_t = S_t - C_t identically (both branches are prev' = prev + a - [fire]),
// so C_t = C_{t-1} + [S_t - C_{t-1} > 1] = min(C_{t-1}+1, Kp_t) with
// Kp_t = max(0, ceil(S_t - 1)) (nondecreasing since a >= 0). Exact solution:
//   C_t = t + min(1, M_t),  M_t = min_{s<=t}(Kp_s - s).
// Valid for ANY a_t >= 0 (handles scale > 1 / double-pressure exactly).
__global__ void __launch_bounds__(256) k2_weights(
    const double* __restrict__ d1, const double* __restrict__ d2,
    const float* __restrict__ absS, const float* __restrict__ mask,
    const int* __restrict__ is_tr, const double* __restrict__ c0p,
    float* __restrict__ o_ori, float* __restrict__ o_sa, float* __restrict__ o_ff,
    float* __restrict__ wsc, int* __restrict__ fireT,
    int* __restrict__ nAllArr, int* __restrict__ nUnmArr) {
  __shared__ double s_P[T_];        // prefix sums of d2 (16 KB)
  __shared__ double s_tot[4];       // wave totals (cumsum #1)
  __shared__ double s_red[4][3];    // wave partials: sumA, fpc, maskSum
  __shared__ double s_tot2[4];      // wave totals (cumsum #2)
  __shared__ double s_mtot[4];      // wave mins (min-scan)
  __shared__ int s_int[2];          // [0]=C@firstPad, [1]=nA
  int b = blockIdx.x, tid = threadIdx.x;
  int lane = tid & 63, wv = tid >> 6;
  int t0 = tid * 8;                 // 8 contiguous elements per thread
  const double* d1b = d1 + (long)b * T_;
  const double* d2b = d2 + (long)b * T_;
  const float* asb = absS + (long)b * T_;
  double c0 = c0p[0];

  // ---- prefix sum of d2 -> s_P ----
  double r2[8];
  {
    double run2 = 0.0;
#pragma unroll
    for (int k = 0; k < 8; ++k) { run2 += d2b[t0 + k]; r2[k] = run2; }
    double sc2 = run2;
#pragma unroll
    for (int off = 1; off < 64; off <<= 1) {
      double n = __shfl_up(sc2, off, 64);
      if (lane >= off) sc2 += n;
    }
    if (lane == 63) s_tot[wv] = sc2;
    __syncthreads();
    double base2 = 0.0;
    for (int i = 0; i < wv; ++i) base2 += s_tot[i];
    double e2 = base2 + (sc2 - run2);
#pragma unroll
    for (int k = 0; k < 8; ++k) s_P[t0 + k] = e2 + r2[k];
  }
  __syncthreads();

  // ---- Part A: w = clip(relu(d1 - windowmean + c0), 0, 1); windowsum via P
  double wd[8];
  double sa = 0.0, fpc = 0.0;
#pragma unroll
  for (int k = 0; k < 8; ++k) {
    int t = t0 + k;
    double wvv;
    if (t == 0) {
      wvv = d1b[0] - s_P[0] + c0;  // hist[0] = x[0]
    } else {
      int start = t - 10; if (start < 0) start = 0;
      double ws_ = s_P[t - 1] - (start > 0 ? s_P[start - 1] : 0.0);
      wvv = d1b[t] - ws_ / (double)(t - start) + c0;
    }
    wvv = wvv < 0.0 ? 0.0 : (wvv > 1.0 ? 1.0 : wvv);
    wd[k] = wvv;
    sa += wvv;
    fpc += (asb[t] != 0.0f) ? 1.0 : 0.0;
  }
  {  // o_ori: two float4 stores (contiguous 8)
    float4* ov = (float4*)(o_ori + (long)b * T_ + t0);
    ov[0] = make_float4((float)wd[0], (float)wd[1], (float)wd[2], (float)wd[3]);
    ov[1] = make_float4((float)wd[4], (float)wd[5], (float)wd[6], (float)wd[7]);
  }
  // ---- reductions via wave shuffles (sumA, firstPad count, maskSum)
  double ms = (tid < 200) ? (double)mask[(long)b * 200 + tid] : 0.0;
  double sar = waveReduceD(sa), fpr = waveReduceD(fpc), msr = waveReduceD(ms);
  if (lane == 0) { s_red[wv][0] = sar; s_red[wv][1] = fpr; s_red[wv][2] = msr; }
  __syncthreads();
  double sumA = s_red[0][0] + s_red[1][0] + s_red[2][0] + s_red[3][0];
  double fpD  = s_red[0][1] + s_red[1][1] + s_red[2][1] + s_red[3][1];
  double maskSum = s_red[0][2] + s_red[1][2] + s_red[2][2] + s_red[3][2];
  if (tid == 0) o_sa[b] = (float)sumA;
  int firstPad = (int)(fpD + 0.5);
  double scale;
  if (is_tr[0] != 0) {
    scale = (sumA == 0.0) ? 0.0 : (maskSum - 1.0) / (sumA > 1e-8 ? sumA : 1e-8);
  } else {
    scale = 1.0;
  }

  // ---- scaled + pad-masked a; write wsc; cumsum -> S_t
  double a[8], r[8];
  double run = 0.0;
#pragma unroll
  for (int k = 0; k < 8; ++k) {
    int t = t0 + k;
    double av = wd[k] * scale;
    if (t > firstPad) av = 0.0;
    a[k] = av;
    run += av; r[k] = run;
  }
  {  // wsc: two float4 stores
    float4* wvv = (float4*)(wsc + (long)b * T_ + t0);
    wvv[0] = make_float4((float)a[0], (float)a[1], (float)a[2], (float)a[3]);
    wvv[1] = make_float4((float)a[4], (float)a[5], (float)a[6], (float)a[7]);
  }
  double sc = run;
#pragma unroll
  for (int off = 1; off < 64; off <<= 1) {
    double n = __shfl_up(sc, off, 64);
    if (lane >= off) sc += n;
  }
  if (lane == 63) s_tot2[wv] = sc;
  __syncthreads();
  double base = 0.0;
  for (int i = 0; i < wv; ++i) base += s_tot2[i];
  double e = base + (sc - run);  // exclusive prefix for this thread

  // ---- D_t = Kp_t - t, prefix-min scan -> M_t, C_t = t + min(1, M_t)
  double m[8];
  double mn = 1e300;
#pragma unroll
  for (int k = 0; k < 8; ++k) {
    double S = e + r[k];
    double kp = ceil(S - 1.0); if (kp < 0.0) kp = 0.0;
    double D = kp - (double)(t0 + k);
    mn = fmin(mn, D);
    m[k] = mn;
  }
  double scm = mn;
#pragma unroll
  for (int off = 1; off < 64; off <<= 1) {
    double n = __shfl_up(scm, off, 64);
    if (lane >= off) scm = fmin(scm, n);
  }
  double exw = __shfl_up(scm, 1, 64);       // wave-exclusive inclusive-min
  if (lane == 0) exw = 1e300;
  if (lane == 63) s_mtot[wv] = scm;
  __syncthreads();
  double mbase = 1e300;
  for (int i = 0; i < wv; ++i) mbase = fmin(mbase, s_mtot[i]);
  double Mexcl = fmin(mbase, exw);          // min over s < t0

  // ---- fires ----
  float flags[8];
  int Cp = (t0 - 1) + (int)fmin(1.0, Mexcl);  // t0==0: Mexcl=inf -> C_{-1}=0
#pragma unroll
  for (int k = 0; k < 8; ++k) {
    int t = t0 + k;
    double Mk = fmin(Mexcl, m[k]);
    int C = t + (int)fmin(1.0, Mk);
    bool fired = C > Cp;
    flags[k] = fired ? 1.0f : 0.0f;
    if (fired) fireT[(long)b * T_ + (C - 1)] = t;
    if (t == firstPad) s_int[0] = C;
    Cp = C;
  }
  {  // o_ff: two float4 stores
    float4* fv = (float4*)(o_ff + (long)b * T_ + t0);
    fv[0] = make_float4(flags[0], flags[1], flags[2], flags[3]);
    fv[1] = make_float4(flags[4], flags[5], flags[6], flags[7]);
  }
  if (tid == 255) s_int[1] = Cp;  // nA = C_{T-1}
  __syncthreads();
  if (tid == 0) {
    int nA = s_int[1];
    nAllArr[b] = nA;
    nUnmArr[b] = (firstPad >= T_) ? nA : s_int[0];
  }
}

// ---------------- K4: ALL cif rows (work rows + zero rows) ----------------
// grid (ceil(L/4), B), 256 threads = 4 waves, one pos per wave. Full
// coverage of cif + notpad -> no memset needed.  Fires with t<=firstPad are
// ranks [0,nU) (pad-region fires only ever follow them), so row pos < nU is
// the segment ending at fireT[pos]; pos == nU is the final carry state.
__global__ void __launch_bounds__(256) k4_rows(
    const float* __restrict__ x, const float* __restrict__ wsc,
    const int* __restrict__ fireT,
    const int* __restrict__ nAllArr, const int* __restrict__ nUnmArr,
    float* __restrict__ cif, float* __restrict__ notpad) {
  int wave = threadIdx.x >> 6, lane = threadIdx.x & 63;
  int pos = blockIdx.x * 4 + wave;
  int b = blockIdx.y;
  if (pos >= L_) return;
  int nA = nAllArr[b], nU = nUnmArr[b];
  float4* crow = (float4*)(cif + ((long)b * L_ + pos) * H_);
  if (pos > nU) {
    crow[lane] = make_float4(0.0f, 0.0f, 0.0f, 0.0f);
    if (lane == 0) notpad[(long)b * L_ + pos] = 0.0f;
    return;
  }
  const int* ftb = fireT + (long)b * T_;
  int hi, anchor, lo;
  if (pos < nU) {
    hi = ftb[pos];
    anchor = (pos == 0) ? 0 : ftb[pos - 1];
    lo = (pos == 0) ? 0 : anchor + 1;
  } else {
    hi = T_ - 1;                       // final carry state fin_s
    anchor = (nA == 0) ? 0 : ftb[nA - 1];
    lo = (nA == 0) ? 0 : anchor + 1;
  }
  const float* xb = x + (long)b * T_ * H_;
  float4 acc = ((const float4*)(xb + (long)anchor * H_))[lane];
  const float* wb = wsc + (long)b * T_;
  for (int u = lo; u <= hi; ++u) {
    float f = 1.0f - wb[u];
    float4 xv = ((const float4*)(xb + (long)u * H_))[lane];
    acc.x += f * xv.x; acc.y += f * xv.y; acc.z += f * xv.z; acc.w += f * xv.w;
  }
  float ss = acc.x * acc.x + acc.y * acc.y + acc.z * acc.z + acc.w * acc.w;
#pragma unroll
  for (int off = 32; off > 0; off >>= 1) ss += __shfl_xor(ss, off, 64);
  float inv = 1.0f / fmaxf(sqrtf(ss), 1e-12f);
  crow[lane] = make_float4(acc.x * inv, acc.y * inv, acc.z * inv, acc.w * inv);
  if (lane == 0) notpad[(long)b * L_ + pos] = 1.0f;
}

// ---------------- launch ----------------
extern "C" void kernel_launch(void* const* d_in, const int* in_sizes, int n_in,
                              void* d_out, int out_size, void* d_ws, size_t ws_size,
                              hipStream_t stream) {
  const float* x    = (const float*)d_in[0];
  const float* mask = (const float*)d_in[1];
  const float* W1   = (const float*)d_in[2];
  const float* b1   = (const float*)d_in[3];
  const float* W2   = (const float*)d_in[4];
  const float* b2   = (const float*)d_in[5];
  const int*   istr = (const int*)d_in[6];

  float* out = (float*)d_out;
  // output layout (all fp32, concatenated in return order)
  float* o_cif = out;                                  // B*L*H
  float* o_ori = o_cif + (size_t)B_ * L_ * H_;         // B*T
  float* o_ff  = o_ori + (size_t)B_ * T_;              // B*T
  float* o_np  = o_ff  + (size_t)B_ * T_;              // B*L
  float* o_sa  = o_np  + (size_t)B_ * L_;              // B

  // workspace layout
  char* w = (char*)d_ws;
  double* vd   = (double*)w; w += 512 * 8;
  double* c0   = (double*)w; w += 8;
  double* d1   = (double*)w; w += (size_t)B_ * T_ * 8;
  double* d2   = (double*)w; w += (size_t)B_ * T_ * 8;
  float* absS  = (float*)w;  w += (size_t)B_ * T_ * 4;
  float* wsc   = (float*)w;  w += (size_t)B_ * T_ * 4;
  int* fireT   = (int*)w;    w += (size_t)B_ * T_ * 4;
  int* nAllA   = (int*)w;    w += B_ * 4;
  int* nUnmA   = (int*)w;    w += B_ * 4;

  // no memset: k2 covers o_ori/o_ff/o_sa; k4 covers every cif row + o_np.
  k0_fold<<<16, 256, 0, stream>>>(W1, b1, W2, b2, vd, c0);
  k1_rowdots<<<(B_ * T_) / 4, 256, 0, stream>>>(x, vd, d1, d2, absS);
  k2_weights<<<B_, 256, 0, stream>>>(d1, d2, absS, mask, istr, c0,
                                     o_ori, o_sa, o_ff, wsc, fireT,
                                     nAllA, nUnmA);
  k4_rows<<<dim3((L_ + 3) / 4, B_), 256, 0, stream>>>(
      x, wsc, fireT, nAllA, nUnmA, o_cif, o_np);
}

// Round 6
// 151.982 us; speedup vs baseline: 1.5380x; 1.0234x over previous
//
#include <hip/hip_runtime.h>

#define B_ 32
#define T_ 2048
#define H_ 256
#define L_ 2049   // T_ + 1

// ---------------- helpers ----------------
__device__ inline double waveReduceD(double v) {
#pragma unroll
  for (int off = 32; off > 0; off >>= 1) v += __shfl_xor(v, off, 64);
  return v;
}

typedef float vfloat4 __attribute__((ext_vector_type(4)));
__device__ inline void nt_store4(float4 v, float* p) {
  vfloat4 t;
  t.x = v.x; t.y = v.y; t.z = v.z; t.w = v.w;
  __builtin_nontemporal_store(t, (vfloat4*)p);
}

// ---------------- K0: fold the two linear layers ----------------
// v[c] = sum_o W2[o] * W1[o,c]  (c in [0,512)),  c0 = W2.b1 + b2
__global__ void __launch_bounds__(256) k0_fold(
    const float* __restrict__ W1, const float* __restrict__ b1,
    const float* __restrict__ W2, const float* __restrict__ b2,
    double* __restrict__ vd, double* __restrict__ c0) {
  __shared__ double s_p[8][32];
  int tid = threadIdx.x;
  int cl = tid & 31, sl = tid >> 5;
  int c = blockIdx.x * 32 + cl;
  double acc = 0.0;
#pragma unroll 8
  for (int o = sl * 64; o < sl * 64 + 64; ++o)
    acc += (double)W2[o] * (double)W1[o * 512 + c];
  s_p[sl][cl] = acc;
  __syncthreads();
  if (sl == 0) {
    double v = 0.0;
#pragma unroll
    for (int i = 0; i < 8; ++i) v += s_p[i][cl];
    vd[c] = v;
  }
  if (blockIdx.x == 0) {
    __shared__ double red[256];
    double p = (double)W2[tid] * (double)b1[tid] +
               (double)W2[tid + 256] * (double)b1[tid + 256];
    red[tid] = p;
    __syncthreads();
    for (int s = 128; s > 0; s >>= 1) {
      if (tid < s) red[tid] += red[tid + s];
      __syncthreads();
    }
    if (tid == 0) c0[0] = red[0] + (double)b2[0];
  }
}

// ---------------- K1: per-(b,t) row dots, 4 rows per wave ----------------
// d1[r] = x_row.(v1+v2), d2[r] = x_row.v2, absS[r] = (any nonzero) ? 1 : 0
__global__ void __launch_bounds__(256) k1_rowdots(
    const float* __restrict__ x, const double* __restrict__ vd,
    double* __restrict__ d1, double* __restrict__ d2, float* __restrict__ absS) {
  int wave = threadIdx.x >> 6, lane = threadIdx.x & 63;
  long row0 = ((long)blockIdx.x * 4 + wave) * 4;  // 4 consecutive rows
  const float4* xr = (const float4*)(x + row0 * H_);
  float4 x0 = xr[lane];
  float4 x1 = xr[lane + 64];
  float4 x2 = xr[lane + 128];
  float4 x3 = xr[lane + 192];
  int base = lane * 4;
  double vb0 = vd[256 + base + 0], vb1 = vd[256 + base + 1],
         vb2 = vd[256 + base + 2], vb3 = vd[256 + base + 3];
  double va0 = vd[base + 0] + vb0, va1 = vd[base + 1] + vb1,
         va2 = vd[base + 2] + vb2, va3 = vd[base + 3] + vb3;
  double p10 = (double)x0.x * va0 + (double)x0.y * va1 + (double)x0.z * va2 + (double)x0.w * va3;
  double p20 = (double)x0.x * vb0 + (double)x0.y * vb1 + (double)x0.z * vb2 + (double)x0.w * vb3;
  double p11 = (double)x1.x * va0 + (double)x1.y * va1 + (double)x1.z * va2 + (double)x1.w * va3;
  double p21 = (double)x1.x * vb0 + (double)x1.y * vb1 + (double)x1.z * vb2 + (double)x1.w * vb3;
  double p12 = (double)x2.x * va0 + (double)x2.y * va1 + (double)x2.z * va2 + (double)x2.w * va3;
  double p22 = (double)x2.x * vb0 + (double)x2.y * vb1 + (double)x2.z * vb2 + (double)x2.w * vb3;
  double p13 = (double)x3.x * va0 + (double)x3.y * va1 + (double)x3.z * va2 + (double)x3.w * va3;
  double p23 = (double)x3.x * vb0 + (double)x3.y * vb1 + (double)x3.z * vb2 + (double)x3.w * vb3;
  bool n0 = (x0.x != 0.0f) || (x0.y != 0.0f) || (x0.z != 0.0f) || (x0.w != 0.0f);
  bool n1 = (x1.x != 0.0f) || (x1.y != 0.0f) || (x1.z != 0.0f) || (x1.w != 0.0f);
  bool n2 = (x2.x != 0.0f) || (x2.y != 0.0f) || (x2.z != 0.0f) || (x2.w != 0.0f);
  bool n3 = (x3.x != 0.0f) || (x3.y != 0.0f) || (x3.z != 0.0f) || (x3.w != 0.0f);
  unsigned long long b0 = __ballot(n0), b1_ = __ballot(n1),
                     b2_ = __ballot(n2), b3 = __ballot(n3);
  // 8 interleaved butterflies — independent chains hide ds latency
#pragma unroll
  for (int off = 32; off > 0; off >>= 1) {
    p10 += __shfl_xor(p10, off, 64);
    p20 += __shfl_xor(p20, off, 64);
    p11 += __shfl_xor(p11, off, 64);
    p21 += __shfl_xor(p21, off, 64);
    p12 += __shfl_xor(p12, off, 64);
    p22 += __shfl_xor(p22, off, 64);
    p13 += __shfl_xor(p13, off, 64);
    p23 += __shfl_xor(p23, off, 64);
  }
  if (lane == 0)       { d1[row0 + 0] = p10; d2[row0 + 0] = p20; absS[row0 + 0] = b0  ? 1.0f : 0.0f; }
  else if (lane == 16) { d1[row0 + 1] = p11; d2[row0 + 1] = p21; absS[row0 + 1] = b1_ ? 1.0f : 0.0f; }
  else if (lane == 32) { d1[row0 + 2] = p12; d2[row0 + 2] = p22; absS[row0 + 2] = b2_ ? 1.0f : 0.0f; }
  else if (lane == 48) { d1[row0 + 3] = p13; d2[row0 + 3] = p23; absS[row0 + 3] = b3  ? 1.0f : 0.0f; }
}

// ---------------- K2: weights + EXACT parallel fire solve (1 block / b) --
// prev_t = S_t - C_t identically, so C_t = min(C_{t-1}+1, Kp_t) with
// Kp_t = max(0, ceil(S_t - 1)) nondecreasing. Exact solution:
//   C_t = t + min(1, M_t),  M_t = min_{s<=t}(Kp_s - s).   (any a_t >= 0)
__global__ void __launch_bounds__(256) k2_weights(
    const double* __restrict__ d1, const double* __restrict__ d2,
    const float* __restrict__ absS, const float* __restrict__ mask,
    const int* __restrict__ is_tr, const double* __restrict__ c0p,
    float* __restrict__ o_ori, float* __restrict__ o_sa, float* __restrict__ o_ff,
    float* __restrict__ wsc, int* __restrict__ fireT,
    int* __restrict__ nAllArr, int* __restrict__ nUnmArr) {
  __shared__ double s_P[T_];        // prefix sums of d2 (16 KB)
  __shared__ double s_tot[4];       // wave totals (cumsum #1)
  __shared__ double s_red[4][3];    // wave partials: sumA, fpc, maskSum
  __shared__ double s_tot2[4];      // wave totals (cumsum #2)
  __shared__ double s_mtot[4];      // wave mins (min-scan)
  __shared__ int s_int[2];          // [0]=C@firstPad, [1]=nA
  int b = blockIdx.x, tid = threadIdx.x;
  int lane = tid & 63, wv = tid >> 6;
  int t0 = tid * 8;                 // 8 contiguous elements per thread
  const double* d1b = d1 + (long)b * T_;
  const double* d2b = d2 + (long)b * T_;
  const float* asb = absS + (long)b * T_;
  double c0 = c0p[0];

  // ---- prefix sum of d2 -> s_P ----
  double r2[8];
  {
    double run2 = 0.0;
#pragma unroll
    for (int k = 0; k < 8; ++k) { run2 += d2b[t0 + k]; r2[k] = run2; }
    double sc2 = run2;
#pragma unroll
    for (int off = 1; off < 64; off <<= 1) {
      double n = __shfl_up(sc2, off, 64);
      if (lane >= off) sc2 += n;
    }
    if (lane == 63) s_tot[wv] = sc2;
    __syncthreads();
    double base2 = 0.0;
    for (int i = 0; i < wv; ++i) base2 += s_tot[i];
    double e2 = base2 + (sc2 - run2);
#pragma unroll
    for (int k = 0; k < 8; ++k) s_P[t0 + k] = e2 + r2[k];
  }
  __syncthreads();

  // ---- Part A: w = clip(relu(d1 - windowmean + c0), 0, 1); windowsum via P
  double wd[8];
  double sa = 0.0, fpc = 0.0;
#pragma unroll
  for (int k = 0; k < 8; ++k) {
    int t = t0 + k;
    double wvv;
    if (t == 0) {
      wvv = d1b[0] - s_P[0] + c0;  // hist[0] = x[0]
    } else {
      int start = t - 10; if (start < 0) start = 0;
      double ws_ = s_P[t - 1] - (start > 0 ? s_P[start - 1] : 0.0);
      wvv = d1b[t] - ws_ / (double)(t - start) + c0;
    }
    wvv = wvv < 0.0 ? 0.0 : (wvv > 1.0 ? 1.0 : wvv);
    wd[k] = wvv;
    sa += wvv;
    fpc += (asb[t] != 0.0f) ? 1.0 : 0.0;
  }
  {  // o_ori: two float4 stores (contiguous 8)
    float4* ov = (float4*)(o_ori + (long)b * T_ + t0);
    ov[0] = make_float4((float)wd[0], (float)wd[1], (float)wd[2], (float)wd[3]);
    ov[1] = make_float4((float)wd[4], (float)wd[5], (float)wd[6], (float)wd[7]);
  }
  // ---- reductions via wave shuffles (sumA, firstPad count, maskSum)
  double ms = (tid < 200) ? (double)mask[(long)b * 200 + tid] : 0.0;
  double sar = waveReduceD(sa), fpr = waveReduceD(fpc), msr = waveReduceD(ms);
  if (lane == 0) { s_red[wv][0] = sar; s_red[wv][1] = fpr; s_red[wv][2] = msr; }
  __syncthreads();
  double sumA = s_red[0][0] + s_red[1][0] + s_red[2][0] + s_red[3][0];
  double fpD  = s_red[0][1] + s_red[1][1] + s_red[2][1] + s_red[3][1];
  double maskSum = s_red[0][2] + s_red[1][2] + s_red[2][2] + s_red[3][2];
  if (tid == 0) o_sa[b] = (float)sumA;
  int firstPad = (int)(fpD + 0.5);
  double scale;
  if (is_tr[0] != 0) {
    scale = (sumA == 0.0) ? 0.0 : (maskSum - 1.0) / (sumA > 1e-8 ? sumA : 1e-8);
  } else {
    scale = 1.0;
  }

  // ---- scaled + pad-masked a; write wsc; cumsum -> S_t
  double a[8], r[8];
  double run = 0.0;
#pragma unroll
  for (int k = 0; k < 8; ++k) {
    int t = t0 + k;
    double av = wd[k] * scale;
    if (t > firstPad) av = 0.0;
    a[k] = av;
    run += av; r[k] = run;
  }
  {  // wsc: two float4 stores
    float4* wvv = (float4*)(wsc + (long)b * T_ + t0);
    wvv[0] = make_float4((float)a[0], (float)a[1], (float)a[2], (float)a[3]);
    wvv[1] = make_float4((float)a[4], (float)a[5], (float)a[6], (float)a[7]);
  }
  double sc = run;
#pragma unroll
  for (int off = 1; off < 64; off <<= 1) {
    double n = __shfl_up(sc, off, 64);
    if (lane >= off) sc += n;
  }
  if (lane == 63) s_tot2[wv] = sc;
  __syncthreads();
  double base = 0.0;
  for (int i = 0; i < wv; ++i) base += s_tot2[i];
  double e = base + (sc - run);  // exclusive prefix for this thread

  // ---- D_t = Kp_t - t, prefix-min scan -> M_t, C_t = t + min(1, M_t)
  double m[8];
  double mn = 1e300;
#pragma unroll
  for (int k = 0; k < 8; ++k) {
    double S = e + r[k];
    double kp = ceil(S - 1.0); if (kp < 0.0) kp = 0.0;
    double D = kp - (double)(t0 + k);
    mn = fmin(mn, D);
    m[k] = mn;
  }
  double scm = mn;
#pragma unroll
  for (int off = 1; off < 64; off <<= 1) {
    double n = __shfl_up(scm, off, 64);
    if (lane >= off) scm = fmin(scm, n);
  }
  double exw = __shfl_up(scm, 1, 64);       // wave-exclusive inclusive-min
  if (lane == 0) exw = 1e300;
  if (lane == 63) s_mtot[wv] = scm;
  __syncthreads();
  double mbase = 1e300;
  for (int i = 0; i < wv; ++i) mbase = fmin(mbase, s_mtot[i]);
  double Mexcl = fmin(mbase, exw);          // min over s < t0

  // ---- fires ----
  float flags[8];
  int Cp = (t0 - 1) + (int)fmin(1.0, Mexcl);  // t0==0: Mexcl=inf -> C_{-1}=0
#pragma unroll
  for (int k = 0; k < 8; ++k) {
    int t = t0 + k;
    double Mk = fmin(Mexcl, m[k]);
    int C = t + (int)fmin(1.0, Mk);
    bool fired = C > Cp;
    flags[k] = fired ? 1.0f : 0.0f;
    if (fired) fireT[(long)b * T_ + (C - 1)] = t;
    if (t == firstPad) s_int[0] = C;
    Cp = C;
  }
  {  // o_ff: two float4 stores
    float4* fv = (float4*)(o_ff + (long)b * T_ + t0);
    fv[0] = make_float4(flags[0], flags[1], flags[2], flags[3]);
    fv[1] = make_float4(flags[4], flags[5], flags[6], flags[7]);
  }
  if (tid == 255) s_int[1] = Cp;  // nA = C_{T-1}
  __syncthreads();
  if (tid == 0) {
    int nA = s_int[1];
    nAllArr[b] = nA;
    nUnmArr[b] = (firstPad >= T_) ? nA : s_int[0];
  }
}

// ---------------- K4: ALL cif rows (work rows + zero rows) ----------------
// grid (ceil(L/4), B), 256 threads = 4 waves, one pos per wave. Full
// coverage of cif + notpad -> no memset needed. Nontemporal stores keep the
// 67 MB cif stream from evicting x out of L2/L3 (k4 re-reads x after k1).
__global__ void __launch_bounds__(256) k4_rows(
    const float* __restrict__ x, const float* __restrict__ wsc,
    const int* __restrict__ fireT,
    const int* __restrict__ nAllArr, const int* __restrict__ nUnmArr,
    float* __restrict__ cif, float* __restrict__ notpad) {
  int wave = threadIdx.x >> 6, lane = threadIdx.x & 63;
  int pos = blockIdx.x * 4 + wave;
  int b = blockIdx.y;
  if (pos >= L_) return;
  int nA = nAllArr[b], nU = nUnmArr[b];
  float* crow = cif + ((long)b * L_ + pos) * H_ + lane * 4;
  if (pos > nU) {
    nt_store4(make_float4(0.0f, 0.0f, 0.0f, 0.0f), crow);
    if (lane == 0) notpad[(long)b * L_ + pos] = 0.0f;
    return;
  }
  const int* ftb = fireT + (long)b * T_;
  int hi, anchor, lo;
  if (pos < nU) {
    hi = ftb[pos];
    anchor = (pos == 0) ? 0 : ftb[pos - 1];
    lo = (pos == 0) ? 0 : anchor + 1;
  } else {
    hi = T_ - 1;                       // final carry state fin_s
    anchor = (nA == 0) ? 0 : ftb[nA - 1];
    lo = (nA == 0) ? 0 : anchor + 1;
  }
  const float* xb = x + (long)b * T_ * H_;
  float4 acc = ((const float4*)(xb + (long)anchor * H_))[lane];
  float4 acc2 = make_float4(0.0f, 0.0f, 0.0f, 0.0f);
  const float* wb = wsc + (long)b * T_;
  int u = lo;
  for (; u + 1 <= hi; u += 2) {   // dual accumulators: half the dep chain
    float f0 = 1.0f - wb[u];
    float f1 = 1.0f - wb[u + 1];
    float4 xv0 = ((const float4*)(xb + (long)u * H_))[lane];
    float4 xv1 = ((const float4*)(xb + (long)(u + 1) * H_))[lane];
    acc.x += f0 * xv0.x;  acc.y += f0 * xv0.y;
    acc.z += f0 * xv0.z;  acc.w += f0 * xv0.w;
    acc2.x += f1 * xv1.x; acc2.y += f1 * xv1.y;
    acc2.z += f1 * xv1.z; acc2.w += f1 * xv1.w;
  }
  if (u <= hi) {
    float f = 1.0f - wb[u];
    float4 xv = ((const float4*)(xb + (long)u * H_))[lane];
    acc.x += f * xv.x; acc.y += f * xv.y; acc.z += f * xv.z; acc.w += f * xv.w;
  }
  acc.x += acc2.x; acc.y += acc2.y; acc.z += acc2.z; acc.w += acc2.w;
  float ss = acc.x * acc.x + acc.y * acc.y + acc.z * acc.z + acc.w * acc.w;
#pragma unroll
  for (int off = 32; off > 0; off >>= 1) ss += __shfl_xor(ss, off, 64);
  float inv = 1.0f / fmaxf(sqrtf(ss), 1e-12f);
  nt_store4(make_float4(acc.x * inv, acc.y * inv, acc.z * inv, acc.w * inv), crow);
  if (lane == 0) notpad[(long)b * L_ + pos] = 1.0f;
}

// ---------------- launch ----------------
extern "C" void kernel_launch(void* const* d_in, const int* in_sizes, int n_in,
                              void* d_out, int out_size, void* d_ws, size_t ws_size,
                              hipStream_t stream) {
  const float* x    = (const float*)d_in[0];
  const float* mask = (const float*)d_in[1];
  const float* W1   = (const float*)d_in[2];
  const float* b1   = (const float*)d_in[3];
  const float* W2   = (const float*)d_in[4];
  const float* b2   = (const float*)d_in[5];
  const int*   istr = (const int*)d_in[6];

  float* out = (float*)d_out;
  // output layout (all fp32, concatenated in return order)
  float* o_cif = out;                                  // B*L*H
  float* o_ori = o_cif + (size_t)B_ * L_ * H_;         // B*T
  float* o_ff  = o_ori + (size_t)B_ * T_;              // B*T
  float* o_np  = o_ff  + (size_t)B_ * T_;              // B*L
  float* o_sa  = o_np  + (size_t)B_ * L_;              // B

  // workspace layout
  char* w = (char*)d_ws;
  double* vd   = (double*)w; w += 512 * 8;
  double* c0   = (double*)w; w += 8;
  double* d1   = (double*)w; w += (size_t)B_ * T_ * 8;
  double* d2   = (double*)w; w += (size_t)B_ * T_ * 8;
  float* absS  = (float*)w;  w += (size_t)B_ * T_ * 4;
  float* wsc   = (float*)w;  w += (size_t)B_ * T_ * 4;
  int* fireT   = (int*)w;    w += (size_t)B_ * T_ * 4;
  int* nAllA   = (int*)w;    w += B_ * 4;
  int* nUnmA   = (int*)w;    w += B_ * 4;

  // no memset: k2 covers o_ori/o_ff/o_sa; k4 covers every cif row + o_np.
  k0_fold<<<16, 256, 0, stream>>>(W1, b1, W2, b2, vd, c0);
  k1_rowdots<<<(B_ * T_) / 16, 256, 0, stream>>>(x, vd, d1, d2, absS);
  k2_weights<<<B_, 256, 0, stream>>>(d1, d2, absS, mask, istr, c0,
                                     o_ori, o_sa, o_ff, wsc, fireT,
                                     nAllA, nUnmA);
  k4_rows<<<dim3((L_ + 3) / 4, B_), 256, 0, stream>>>(
      x, wsc, fireT, nAllA, nUnmA, o_cif, o_np);
}